// Round 1
// baseline (477.587 us; speedup 1.0000x reference)
//
#include <hip/hip_runtime.h>
#include <cstdint>
#include <cstddef>

typedef __bf16 bf16;
typedef __attribute__((ext_vector_type(8))) __bf16 bf16x8;
typedef __attribute__((ext_vector_type(4))) __bf16 bf16x4;
typedef __attribute__((ext_vector_type(4))) float f32x4;

#define ATT_SCALE 0.125f   // 1/sqrt(64)
#define NEG_BIG  -1000000000.0f

__device__ __forceinline__ f32x4 mfma16(bf16x8 a, bf16x8 b, f32x4 c) {
  return __builtin_amdgcn_mfma_f32_16x16x32_bf16(a, b, c, 0, 0, 0);
}

__device__ __forceinline__ void gload16(const bf16* g, bf16* l) {
  __builtin_amdgcn_global_load_lds((__attribute__((address_space(1))) void*)g,
                                   (__attribute__((address_space(3))) void*)l,
                                   16, 0, 0);
}

// ---------------- fp32 -> bf16 convert (vectorized) ----------------
__global__ __launch_bounds__(256) void cvt_f32_bf16(const float* __restrict__ in,
                                                    bf16* __restrict__ out, int n4) {
  int i = blockIdx.x * 256 + threadIdx.x;
  if (i < n4) {
    float4 v = *((const float4*)in + i);
    bf16x4 o;
    o[0] = (bf16)v.x; o[1] = (bf16)v.y; o[2] = (bf16)v.z; o[3] = (bf16)v.w;
    *((bf16x4*)out + i) = o;
  }
}

// ---------------- RoPE cos/sin table: [8192][32] ----------------
__global__ __launch_bounds__(256) void rope_table_k(float* __restrict__ cosT,
                                                    float* __restrict__ sinT) {
  int idx = blockIdx.x * 256 + threadIdx.x;   // 8192*32 = 262144
  int t = idx >> 5, j = idx & 31;
  // inv[j] = 10000^(-j/32) = exp2(-j * log2(10000)/32)
  float inv = exp2f(-(float)j * (13.287712379549449f / 32.0f));
  float fr = (float)t * inv;
  cosT[idx] = cosf(fr);
  sinT[idx] = sinf(fr);
}

// ---------------- RoPE apply in-place on qkv (first 2560 cols) ----------------
// one thread per (t, head 0..39, quarter 0..3): handles pairs (d, d+32) for d in [q*8, q*8+8)
__global__ __launch_bounds__(256) void rope_apply(bf16* __restrict__ qkv,
                                                  const float* __restrict__ cosT,
                                                  const float* __restrict__ sinT) {
  int idx = blockIdx.x * 256 + threadIdx.x;   // < 8192*40*4 = 1310720
  int q = idx & 3;
  int h = (idx >> 2) % 40;
  int t = idx / 160;
  int colbase = (h < 32) ? h * 64 : 2048 + (h - 32) * 64;
  int j0 = q * 8;
  bf16* p = qkv + (size_t)t * 3072 + colbase;
  bf16x8 x1 = *(const bf16x8*)(p + j0);
  bf16x8 x2 = *(const bf16x8*)(p + j0 + 32);
  const float* c = cosT + t * 32 + j0;
  const float* s = sinT + t * 32 + j0;
  bf16x8 o1, o2;
#pragma unroll
  for (int e = 0; e < 8; ++e) {
    float cc = c[e], ss = s[e];
    float a = (float)x1[e], b = (float)x2[e];
    o1[e] = (bf16)(a * cc - b * ss);
    o2[e] = (bf16)(b * cc + a * ss);
  }
  *(bf16x8*)(p + j0) = o1;
  *(bf16x8*)(p + j0 + 32) = o2;
}

// ---------------- bf16 GEMM, C[m,n] = sum_k A[m,k]*B[n,k] (B^T form) ----------------
// m97 structure: 128x128 tile, BK=32, 4 waves (2x2 of 64x64), global_load_lds w=16.
// BSEL: B row pointer select across (B0: n<2048 | B1: n<2560 | B2: else), all tile-aligned.
template <int BSEL, int OUTF32>
__global__ __launch_bounds__(256) void gemm_bt(const bf16* __restrict__ A,
                                               const bf16* __restrict__ B0,
                                               const bf16* __restrict__ B1,
                                               const bf16* __restrict__ B2,
                                               void* __restrict__ Cout,
                                               int N, int K) {
  __shared__ bf16 As[128 * 32];
  __shared__ bf16 Bs[128 * 32];
  const int tid = threadIdx.x;
  const int lane = tid & 63, wave = tid >> 6;
  const int m0 = blockIdx.x * 128, n0 = blockIdx.y * 128;
  const int wr = (wave >> 1) * 64, wc = (wave & 1) * 64;

  f32x4 acc[4][4] = {};

  const int srow = tid >> 2;           // 0..63
  const int scol = (tid & 3) * 8;      // 0,8,16,24

  auto brow_ptr = [&](int n) -> const bf16* {
    if (BSEL) {
      if (n < 2048) return B0 + (size_t)n * K;
      if (n < 2560) return B1 + (size_t)(n - 2048) * K;
      return B2 + (size_t)(n - 2560) * K;
    }
    return B0 + (size_t)n * K;
  };

  const bf16* arow0 = A + (size_t)(m0 + srow) * K + scol;
  const bf16* arow1 = A + (size_t)(m0 + 64 + srow) * K + scol;
  const bf16* brow0 = brow_ptr(n0 + srow) + scol;
  const bf16* brow1 = brow_ptr(n0 + 64 + srow) + scol;
  bf16* ldsA = As + wave * 512;   // HW adds lane*16B
  bf16* ldsB = Bs + wave * 512;

  const int fr = lane & 15, fk = (lane >> 4) * 8;

  for (int k0 = 0; k0 < K; k0 += 32) {
    gload16(arow0 + k0, ldsA);
    gload16(arow1 + k0, ldsA + 2048);
    gload16(brow0 + k0, ldsB);
    gload16(brow1 + k0, ldsB + 2048);
    __syncthreads();

    bf16x8 af[4], bfr[4];
#pragma unroll
    for (int m = 0; m < 4; ++m)
      af[m] = *(const bf16x8*)(As + (wr + m * 16 + fr) * 32 + fk);
#pragma unroll
    for (int n = 0; n < 4; ++n)
      bfr[n] = *(const bf16x8*)(Bs + (wc + n * 16 + fr) * 32 + fk);
#pragma unroll
    for (int m = 0; m < 4; ++m)
#pragma unroll
      for (int n = 0; n < 4; ++n)
        acc[m][n] = mfma16(af[m], bfr[n], acc[m][n]);
    __syncthreads();
  }

  // epilogue: C/D layout col=lane&15, row=(lane>>4)*4+i
  const int fc = lane & 15, fr4 = (lane >> 4) * 4;
#pragma unroll
  for (int m = 0; m < 4; ++m)
#pragma unroll
    for (int i = 0; i < 4; ++i) {
      size_t row = (size_t)(m0 + wr + m * 16 + fr4 + i);
#pragma unroll
      for (int n = 0; n < 4; ++n) {
        int col = n0 + wc + n * 16 + fc;
        if (OUTF32)
          ((float*)Cout)[row * (size_t)N + col] = acc[m][n][i];
        else
          ((bf16*)Cout)[row * (size_t)N + col] = (bf16)acc[m][n][i];
      }
    }
}

// ---------------- block-sparse attention ----------------
// grid (128 qblocks, 32 heads), 256 threads = 4 waves; wave w owns q-rows [w*16, w*16+16)
__global__ __launch_bounds__(256) void attn_sparse(const bf16* __restrict__ qkv,
                                                   bf16* __restrict__ attn) {
  const int iblk = blockIdx.x;
  const int h = blockIdx.y;
  const int kv = h >> 2;
  const int tid = threadIdx.x, lane = tid & 63, wid = tid >> 6;

  __shared__ bf16 Qs[64 * 72];
  __shared__ bf16 Ks[64 * 72];
  __shared__ bf16 Vt[64 * 72];   // transposed: Vt[d][key]
  __shared__ bf16 Ps[64 * 72];   // P rows = q rows (wave-private 16-row slices)

  const int qcol = h * 64, kcol = 2048 + kv * 64, vcol = 2560 + kv * 64;
  const size_t trow0 = (size_t)iblk * 64;

  // stage Q
#pragma unroll
  for (int c = 0; c < 2; ++c) {
    int idx = c * 256 + tid;
    int r = idx >> 3, d0 = (idx & 7) * 8;
    bf16x8 v = *(const bf16x8*)(qkv + (trow0 + r) * 3072 + qcol + d0);
    *(bf16x8*)(Qs + r * 72 + d0) = v;
  }
  __syncthreads();

  const int fr = lane & 15, fk = (lane >> 4) * 8;
  bf16x8 aq0 = *(const bf16x8*)(Qs + (wid * 16 + fr) * 72 + fk);
  bf16x8 aq1 = *(const bf16x8*)(Qs + (wid * 16 + fr) * 72 + 32 + fk);

  float mrun[4], lrun[4];
  f32x4 acc[4] = {};
#pragma unroll
  for (int i = 0; i < 4; ++i) { mrun[i] = -INFINITY; lrun[i] = 0.f; }

  const int nsel = (iblk < 8) ? (iblk + 1) : 9;
  for (int js = 0; js < nsel; ++js) {
    const int jblk = (iblk < 8) ? js : ((js == 0) ? 0 : iblk - 8 + js);
    __syncthreads();   // prior iteration done reading Ks/Vt
    // stage K and V^T
#pragma unroll
    for (int c = 0; c < 2; ++c) {
      int idx = c * 256 + tid;
      int r = idx >> 3, d0 = (idx & 7) * 8;
      size_t gbase = ((size_t)jblk * 64 + r) * 3072;
      bf16x8 k8 = *(const bf16x8*)(qkv + gbase + kcol + d0);
      *(bf16x8*)(Ks + r * 72 + d0) = k8;
      bf16x8 v8 = *(const bf16x8*)(qkv + gbase + vcol + d0);
#pragma unroll
      for (int e = 0; e < 8; ++e) Vt[(d0 + e) * 72 + r] = v8[e];
    }
    __syncthreads();

    // S = Q K^T  (16 rows x 64 keys per wave)
    f32x4 s[4];
#pragma unroll
    for (int n = 0; n < 4; ++n) {
      bf16x8 kb0 = *(const bf16x8*)(Ks + (n * 16 + fr) * 72 + fk);
      bf16x8 kb1 = *(const bf16x8*)(Ks + (n * 16 + fr) * 72 + 32 + fk);
      f32x4 z = {};
      z = mfma16(aq0, kb0, z);
      s[n] = mfma16(aq1, kb1, z);
    }

    // scale + causal mask (diag block only)
    const bool diag = (jblk == iblk);
#pragma unroll
    for (int n = 0; n < 4; ++n)
#pragma unroll
      for (int i = 0; i < 4; ++i) {
        float sv = s[n][i] * ATT_SCALE;
        if (diag) {
          int row = wid * 16 + (lane >> 4) * 4 + i;
          int col = n * 16 + (lane & 15);
          if (col > row) sv = NEG_BIG;
        }
        s[n][i] = sv;
      }

    // online softmax per row
#pragma unroll
    for (int i = 0; i < 4; ++i) {
      float mx = fmaxf(fmaxf(s[0][i], s[1][i]), fmaxf(s[2][i], s[3][i]));
#pragma unroll
      for (int d = 1; d < 16; d <<= 1) mx = fmaxf(mx, __shfl_xor(mx, d, 64));
      float mnew = fmaxf(mrun[i], mx);
      float corr = __expf(mrun[i] - mnew);
      mrun[i] = mnew;
      float ps = 0.f;
#pragma unroll
      for (int n = 0; n < 4; ++n) {
        float p = __expf(s[n][i] - mnew);
        s[n][i] = p;
        ps += p;
      }
#pragma unroll
      for (int d = 1; d < 16; d <<= 1) ps += __shfl_xor(ps, d, 64);
      lrun[i] = lrun[i] * corr + ps;
#pragma unroll
      for (int n = 0; n < 4; ++n) acc[n][i] *= corr;
    }

    // write P (bf16) to wave-private LDS rows, re-layout acc->A-operand
#pragma unroll
    for (int n = 0; n < 4; ++n)
#pragma unroll
      for (int i = 0; i < 4; ++i)
        Ps[(wid * 16 + (lane >> 4) * 4 + i) * 72 + n * 16 + (lane & 15)] = (bf16)s[n][i];

    // PV: O += P @ V   (same-wave LDS dependency; compiler inserts lgkmcnt)
    bf16x8 pa0 = *(const bf16x8*)(Ps + (wid * 16 + fr) * 72 + fk);
    bf16x8 pa1 = *(const bf16x8*)(Ps + (wid * 16 + fr) * 72 + 32 + fk);
#pragma unroll
    for (int n = 0; n < 4; ++n) {
      bf16x8 vb0 = *(const bf16x8*)(Vt + (n * 16 + fr) * 72 + fk);
      bf16x8 vb1 = *(const bf16x8*)(Vt + (n * 16 + fr) * 72 + 32 + fk);
      acc[n] = mfma16(pa0, vb0, acc[n]);
      acc[n] = mfma16(pa1, vb1, acc[n]);
    }
  }

  // epilogue: normalize and store bf16
#pragma unroll
  for (int i = 0; i < 4; ++i) {
    float rl = 1.0f / lrun[i];
    size_t t = trow0 + wid * 16 + (lane >> 4) * 4 + i;
#pragma unroll
    for (int n = 0; n < 4; ++n)
      attn[t * 2048 + h * 64 + n * 16 + (lane & 15)] = (bf16)(acc[n][i] * rl);
  }
}

// ---------------- launch ----------------
extern "C" void kernel_launch(void* const* d_in, const int* in_sizes, int n_in,
                              void* d_out, int out_size, void* d_ws, size_t ws_size,
                              hipStream_t stream) {
  (void)in_sizes; (void)n_in; (void)out_size; (void)ws_size;
  const float* hs = (const float*)d_in[0];
  const float* Wq = (const float*)d_in[1];
  const float* Wk = (const float*)d_in[2];
  const float* Wv = (const float*)d_in[3];
  const float* Wo = (const float*)d_in[4];
  float* out = (float*)d_out;

  char* ws = (char*)d_ws;
  bf16* hs16 = (bf16*)(ws + 0);              // 8192*2048*2  = 33554432
  bf16* qkv  = (bf16*)(ws + 33554432);       // 8192*3072*2  = 50331648
  bf16* attn = (bf16*)(ws + 83886080);       // 8192*2048*2  = 33554432
  bf16* wq16 = (bf16*)(ws + 117440512);      // 2048*2048*2  = 8388608
  bf16* wk16 = (bf16*)(ws + 125829120);      // 512*2048*2   = 2097152
  bf16* wv16 = (bf16*)(ws + 127926272);      // 512*2048*2   = 2097152
  bf16* wo16 = (bf16*)(ws + 130023424);      // 2048*2048*2  = 8388608
  float* cosT = (float*)(ws + 138412032);    // 8192*32*4    = 1048576
  float* sinT = (float*)(ws + 139460608);    // 8192*32*4    = 1048576

  cvt_f32_bf16<<<16384, 256, 0, stream>>>(hs, hs16, 4194304);
  cvt_f32_bf16<<<4096, 256, 0, stream>>>(Wq, wq16, 1048576);
  cvt_f32_bf16<<<1024, 256, 0, stream>>>(Wk, wk16, 262144);
  cvt_f32_bf16<<<1024, 256, 0, stream>>>(Wv, wv16, 262144);
  cvt_f32_bf16<<<4096, 256, 0, stream>>>(Wo, wo16, 1048576);
  rope_table_k<<<1024, 256, 0, stream>>>(cosT, sinT);

  // QKV projection: M=8192, N=3072, K=2048
  gemm_bt<1, 0><<<dim3(64, 24), 256, 0, stream>>>(hs16, wq16, wk16, wv16, qkv, 3072, 2048);
  rope_apply<<<5120, 256, 0, stream>>>(qkv, cosT, sinT);
  attn_sparse<<<dim3(128, 32), 256, 0, stream>>>(qkv, attn);
  // O projection: M=8192, N=2048, K=2048, fp32 out
  gemm_bt<0, 1><<<dim3(64, 16), 256, 0, stream>>>(attn, wo16, wo16, wo16, out, 2048, 2048);
}

// Round 2
// 451.751 us; speedup vs baseline: 1.0572x; 1.0572x over previous
//
#include <hip/hip_runtime.h>
#include <cstdint>
#include <cstddef>

typedef __bf16 bf16;
typedef __attribute__((ext_vector_type(8))) __bf16 bf16x8;
typedef __attribute__((ext_vector_type(4))) __bf16 bf16x4;
typedef __attribute__((ext_vector_type(4))) float f32x4;

#define ATT_SCALE 0.125f   // 1/sqrt(64)
#define NEG_BIG  -1000000000.0f

__device__ __forceinline__ f32x4 mfma16(bf16x8 a, bf16x8 b, f32x4 c) {
  return __builtin_amdgcn_mfma_f32_16x16x32_bf16(a, b, c, 0, 0, 0);
}

__device__ __forceinline__ void gload16(const bf16* g, bf16* l) {
  __builtin_amdgcn_global_load_lds((__attribute__((address_space(1))) void*)g,
                                   (__attribute__((address_space(3))) void*)l,
                                   16, 0, 0);
}

// ---------------- fp32 -> bf16 convert (vectorized) ----------------
__global__ __launch_bounds__(256) void cvt_f32_bf16(const float* __restrict__ in,
                                                    bf16* __restrict__ out, int n4) {
  int i = blockIdx.x * 256 + threadIdx.x;
  if (i < n4) {
    float4 v = *((const float4*)in + i);
    bf16x4 o;
    o[0] = (bf16)v.x; o[1] = (bf16)v.y; o[2] = (bf16)v.z; o[3] = (bf16)v.w;
    *((bf16x4*)out + i) = o;
  }
}

// ---------------- RoPE cos/sin table: [8192][32] ----------------
__global__ __launch_bounds__(256) void rope_table_k(float* __restrict__ cosT,
                                                    float* __restrict__ sinT) {
  int idx = blockIdx.x * 256 + threadIdx.x;   // 8192*32 = 262144
  int t = idx >> 5, j = idx & 31;
  float inv = exp2f(-(float)j * (13.287712379549449f / 32.0f));
  float fr = (float)t * inv;
  cosT[idx] = cosf(fr);
  sinT[idx] = sinf(fr);
}

// ---------------- RoPE apply in-place on qkv (first 2560 cols) ----------------
__global__ __launch_bounds__(256) void rope_apply(bf16* __restrict__ qkv,
                                                  const float* __restrict__ cosT,
                                                  const float* __restrict__ sinT) {
  int idx = blockIdx.x * 256 + threadIdx.x;   // < 8192*40*4 = 1310720
  int q = idx & 3;
  int h = (idx >> 2) % 40;
  int t = idx / 160;
  int colbase = (h < 32) ? h * 64 : 2048 + (h - 32) * 64;
  int j0 = q * 8;
  bf16* p = qkv + (size_t)t * 3072 + colbase;
  bf16x8 x1 = *(const bf16x8*)(p + j0);
  bf16x8 x2 = *(const bf16x8*)(p + j0 + 32);
  const float* c = cosT + t * 32 + j0;
  const float* s = sinT + t * 32 + j0;
  bf16x8 o1, o2;
#pragma unroll
  for (int e = 0; e < 8; ++e) {
    float cc = c[e], ss = s[e];
    float a = (float)x1[e], b = (float)x2[e];
    o1[e] = (bf16)(a * cc - b * ss);
    o2[e] = (bf16)(b * cc + a * ss);
  }
  *(bf16x8*)(p + j0) = o1;
  *(bf16x8*)(p + j0 + 32) = o2;
}

// ---------------- bf16 GEMM, C[m,n] = sum_k A[m,k]*B[n,k] (B^T form) ----------------
template <int BSEL, int OUTF32>
__global__ __launch_bounds__(256) void gemm_bt(const bf16* __restrict__ A,
                                               const bf16* __restrict__ B0,
                                               const bf16* __restrict__ B1,
                                               const bf16* __restrict__ B2,
                                               void* __restrict__ Cout,
                                               int N, int K) {
  __shared__ bf16 As[128 * 32];
  __shared__ bf16 Bs[128 * 32];
  const int tid = threadIdx.x;
  const int lane = tid & 63, wave = tid >> 6;
  const int m0 = blockIdx.x * 128, n0 = blockIdx.y * 128;
  const int wr = (wave >> 1) * 64, wc = (wave & 1) * 64;

  f32x4 acc[4][4] = {};

  const int srow = tid >> 2;           // 0..63
  const int scol = (tid & 3) * 8;      // 0,8,16,24

  auto brow_ptr = [&](int n) -> const bf16* {
    if (BSEL) {
      if (n < 2048) return B0 + (size_t)n * K;
      if (n < 2560) return B1 + (size_t)(n - 2048) * K;
      return B2 + (size_t)(n - 2560) * K;
    }
    return B0 + (size_t)n * K;
  };

  const bf16* arow0 = A + (size_t)(m0 + srow) * K + scol;
  const bf16* arow1 = A + (size_t)(m0 + 64 + srow) * K + scol;
  const bf16* brow0 = brow_ptr(n0 + srow) + scol;
  const bf16* brow1 = brow_ptr(n0 + 64 + srow) + scol;
  bf16* ldsA = As + wave * 512;   // HW adds lane*16B
  bf16* ldsB = Bs + wave * 512;

  const int fr = lane & 15, fk = (lane >> 4) * 8;

  for (int k0 = 0; k0 < K; k0 += 32) {
    gload16(arow0 + k0, ldsA);
    gload16(arow1 + k0, ldsA + 2048);
    gload16(brow0 + k0, ldsB);
    gload16(brow1 + k0, ldsB + 2048);
    __syncthreads();

    bf16x8 af[4], bfr[4];
#pragma unroll
    for (int m = 0; m < 4; ++m)
      af[m] = *(const bf16x8*)(As + (wr + m * 16 + fr) * 32 + fk);
#pragma unroll
    for (int n = 0; n < 4; ++n)
      bfr[n] = *(const bf16x8*)(Bs + (wc + n * 16 + fr) * 32 + fk);
#pragma unroll
    for (int m = 0; m < 4; ++m)
#pragma unroll
      for (int n = 0; n < 4; ++n)
        acc[m][n] = mfma16(af[m], bfr[n], acc[m][n]);
    __syncthreads();
  }

  const int fc = lane & 15, fr4 = (lane >> 4) * 4;
#pragma unroll
  for (int m = 0; m < 4; ++m)
#pragma unroll
    for (int i = 0; i < 4; ++i) {
      size_t row = (size_t)(m0 + wr + m * 16 + fr4 + i);
#pragma unroll
      for (int n = 0; n < 4; ++n) {
        int col = n0 + wc + n * 16 + fc;
        if (OUTF32)
          ((float*)Cout)[row * (size_t)N + col] = acc[m][n][i];
        else
          ((bf16*)Cout)[row * (size_t)N + col] = (bf16)acc[m][n][i];
      }
    }
}

// ---------------- block-sparse attention, GQA-grouped ----------------
// grid (128 qblocks, 8 kv heads), 1024 threads = 16 waves.
// wave w: head = kv*4 + (w>>2), q-rows [(w&3)*16, +16). K/V staged once per 4 heads.
// K: global_load_lds into linear [64][64] with XOR slot-swizzle (swizzle applied on
// the GLOBAL source address; LDS dest stays linear — both-sides-or-neither).
// V: packed-dword transpose writes (2 keys -> 1 u32), bank-clean.
__global__ __launch_bounds__(1024) void attn_sparse(const bf16* __restrict__ qkv,
                                                    bf16* __restrict__ attn) {
  const int iblk = blockIdx.x;
  const int kv = blockIdx.y;
  const int tid = threadIdx.x, lane = tid & 63, wid = tid >> 6;
  const int hloc = wid >> 2;          // 0..3
  const int h = kv * 4 + hloc;
  const int rg = wid & 3;             // row-group within the 64-q block

  __shared__ bf16 Ks[64 * 64];        // swizzled: (key r, slot s) at byte r*128 + (s^(r&7))*16
  __shared__ bf16 Vt[64 * 72];        // transposed: Vt[d][key], stride 72
  __shared__ bf16 Ps[16 * 16 * 68];   // per-wave 16 rows, stride 68

  const int qcol = h * 64, kcol = 2048 + kv * 64, vcol = 2560 + kv * 64;
  const size_t trow0 = (size_t)iblk * 64;
  const int fr = lane & 15, g4 = lane >> 4, fk = g4 * 8;
  const int fc = lane & 15, fr4 = g4 * 4;

  // Q fragments in registers (loaded once)
  const bf16* qrow = qkv + (trow0 + rg * 16 + fr) * 3072 + qcol;
  bf16x8 aq0 = *(const bf16x8*)(qrow + fk);
  bf16x8 aq1 = *(const bf16x8*)(qrow + 32 + fk);

  float mrun[4], lrun[4];
  f32x4 acc[4] = {};
#pragma unroll
  for (int i = 0; i < 4; ++i) { mrun[i] = -INFINITY; lrun[i] = 0.f; }

  // staging roles
  const int kr = tid >> 3, ks = tid & 7;                    // tid<512: K row/slot
  const int vu = tid - 512, vp = vu & 31, vd0 = (vu >> 5) * 4;  // tid>=512: V pair/d

  const int nsel = (iblk < 8) ? (iblk + 1) : 9;
  for (int js = 0; js < nsel; ++js) {
    const int jblk = (iblk < 8) ? js : ((js == 0) ? 0 : iblk - 8 + js);
    const size_t krow = (size_t)jblk * 64;
    __syncthreads();   // everyone done reading Ks/Vt from prior step
    if (tid < 512) {
      // K: swizzled source, linear LDS dest (HW: base + lane*16B)
      const bf16* src = qkv + (krow + kr) * 3072 + kcol + ((ks ^ (kr & 7)) * 8);
      bf16* dst = Ks + (tid >> 6) * 512;   // wave-uniform
      gload16(src, dst);
    } else {
      // V transpose: pack keys (2p, 2p+1) for 4 d-values into u32 writes
      const bf16* v0p = qkv + (krow + 2 * vp) * 3072 + vcol + vd0;
      uint64_t a = *(const uint64_t*)v0p;
      uint64_t b = *(const uint64_t*)(v0p + 3072);
#pragma unroll
      for (int e = 0; e < 4; ++e) {
        uint32_t w = (uint32_t)((a >> (16 * e)) & 0xFFFF) |
                     ((uint32_t)((b >> (16 * e)) & 0xFFFF) << 16);
        *(uint32_t*)(Vt + (vd0 + e) * 72 + 2 * vp) = w;
      }
    }
    __syncthreads();

    // S = Q K^T  (16 rows x 64 keys per wave)
    f32x4 s[4];
#pragma unroll
    for (int n = 0; n < 4; ++n) {
      const char* krowp = (const char*)Ks + (n * 16 + fr) * 128;
      bf16x8 kb0 = *(const bf16x8*)(krowp + ((g4 ^ (fr & 7)) << 4));
      bf16x8 kb1 = *(const bf16x8*)(krowp + (((4 + g4) ^ (fr & 7)) << 4));
      f32x4 z = {};
      z = mfma16(aq0, kb0, z);
      s[n] = mfma16(aq1, kb1, z);
    }

    // scale + causal mask (diag block only)
    const bool diag = (jblk == iblk);
#pragma unroll
    for (int n = 0; n < 4; ++n)
#pragma unroll
      for (int i = 0; i < 4; ++i) {
        float sv = s[n][i] * ATT_SCALE;
        if (diag) {
          int row = rg * 16 + fr4 + i;
          int col = n * 16 + fc;
          if (col > row) sv = NEG_BIG;
        }
        s[n][i] = sv;
      }

    // online softmax per row
#pragma unroll
    for (int i = 0; i < 4; ++i) {
      float mx = fmaxf(fmaxf(s[0][i], s[1][i]), fmaxf(s[2][i], s[3][i]));
#pragma unroll
      for (int d = 1; d < 16; d <<= 1) mx = fmaxf(mx, __shfl_xor(mx, d, 64));
      float mnew = fmaxf(mrun[i], mx);
      float corr = __expf(mrun[i] - mnew);
      mrun[i] = mnew;
      float ps = 0.f;
#pragma unroll
      for (int n = 0; n < 4; ++n) {
        float p = __expf(s[n][i] - mnew);
        s[n][i] = p;
        ps += p;
      }
#pragma unroll
      for (int d = 1; d < 16; d <<= 1) ps += __shfl_xor(ps, d, 64);
      lrun[i] = lrun[i] * corr + ps;
#pragma unroll
      for (int n = 0; n < 4; ++n) acc[n][i] *= corr;
    }

    // P -> wave-private LDS (stride 68: row-groups hit banks 0/8/16/24)
    bf16* pbase = Ps + (size_t)wid * 16 * 68;
#pragma unroll
    for (int n = 0; n < 4; ++n)
#pragma unroll
      for (int i = 0; i < 4; ++i)
        pbase[(fr4 + i) * 68 + n * 16 + fc] = (bf16)s[n][i];

    // PV: O += P @ V
    bf16x8 pa0 = *(const bf16x8*)(pbase + fr * 68 + fk);
    bf16x8 pa1 = *(const bf16x8*)(pbase + fr * 68 + 32 + fk);
#pragma unroll
    for (int n = 0; n < 4; ++n) {
      bf16x8 vb0 = *(const bf16x8*)(Vt + (n * 16 + fr) * 72 + fk);
      bf16x8 vb1 = *(const bf16x8*)(Vt + (n * 16 + fr) * 72 + 32 + fk);
      acc[n] = mfma16(pa0, vb0, acc[n]);
      acc[n] = mfma16(pa1, vb1, acc[n]);
    }
  }

  // epilogue: normalize and store bf16
#pragma unroll
  for (int i = 0; i < 4; ++i) {
    float rl = 1.0f / lrun[i];
    size_t t = trow0 + rg * 16 + fr4 + i;
#pragma unroll
    for (int n = 0; n < 4; ++n)
      attn[t * 2048 + h * 64 + n * 16 + fc] = (bf16)(acc[n][i] * rl);
  }
}

// ---------------- launch ----------------
extern "C" void kernel_launch(void* const* d_in, const int* in_sizes, int n_in,
                              void* d_out, int out_size, void* d_ws, size_t ws_size,
                              hipStream_t stream) {
  (void)in_sizes; (void)n_in; (void)out_size; (void)ws_size;
  const float* hs = (const float*)d_in[0];
  const float* Wq = (const float*)d_in[1];
  const float* Wk = (const float*)d_in[2];
  const float* Wv = (const float*)d_in[3];
  const float* Wo = (const float*)d_in[4];
  float* out = (float*)d_out;

  char* ws = (char*)d_ws;
  bf16* hs16 = (bf16*)(ws + 0);              // 8192*2048*2  = 33554432
  bf16* qkv  = (bf16*)(ws + 33554432);       // 8192*3072*2  = 50331648
  bf16* attn = (bf16*)(ws + 83886080);       // 8192*2048*2  = 33554432
  bf16* wq16 = (bf16*)(ws + 117440512);      // 2048*2048*2  = 8388608
  bf16* wk16 = (bf16*)(ws + 125829120);      // 512*2048*2   = 2097152
  bf16* wv16 = (bf16*)(ws + 127926272);      // 512*2048*2   = 2097152
  bf16* wo16 = (bf16*)(ws + 130023424);      // 2048*2048*2  = 8388608
  float* cosT = (float*)(ws + 138412032);    // 8192*32*4    = 1048576
  float* sinT = (float*)(ws + 139460608);    // 8192*32*4    = 1048576

  cvt_f32_bf16<<<16384, 256, 0, stream>>>(hs, hs16, 4194304);
  cvt_f32_bf16<<<4096, 256, 0, stream>>>(Wq, wq16, 1048576);
  cvt_f32_bf16<<<1024, 256, 0, stream>>>(Wk, wk16, 262144);
  cvt_f32_bf16<<<1024, 256, 0, stream>>>(Wv, wv16, 262144);
  cvt_f32_bf16<<<4096, 256, 0, stream>>>(Wo, wo16, 1048576);
  rope_table_k<<<1024, 256, 0, stream>>>(cosT, sinT);

  // QKV projection: M=8192, N=3072, K=2048
  gemm_bt<1, 0><<<dim3(64, 24), 256, 0, stream>>>(hs16, wq16, wk16, wv16, qkv, 3072, 2048);
  rope_apply<<<5120, 256, 0, stream>>>(qkv, cosT, sinT);
  attn_sparse<<<dim3(128, 8), 1024, 0, stream>>>(qkv, attn);
  // O projection: M=8192, N=2048, K=2048, fp32 out
  gemm_bt<0, 1><<<dim3(64, 16), 256, 0, stream>>>(attn, wo16, wo16, wo16, out, 2048, 2048);
}

// Round 3
// 444.383 us; speedup vs baseline: 1.0747x; 1.0166x over previous
//
#include <hip/hip_runtime.h>
#include <cstdint>
#include <cstddef>

typedef __bf16 bf16;
typedef __attribute__((ext_vector_type(8))) __bf16 bf16x8;
typedef __attribute__((ext_vector_type(4))) __bf16 bf16x4;
typedef __attribute__((ext_vector_type(4))) float f32x4;

#define ATT_SCALE 0.125f   // 1/sqrt(64)
#define NEG_BIG  -1000000000.0f

__device__ __forceinline__ f32x4 mfma16(bf16x8 a, bf16x8 b, f32x4 c) {
  return __builtin_amdgcn_mfma_f32_16x16x32_bf16(a, b, c, 0, 0, 0);
}

__device__ __forceinline__ void gload16(const bf16* g, bf16* l) {
  __builtin_amdgcn_global_load_lds((__attribute__((address_space(1))) void*)g,
                                   (__attribute__((address_space(3))) void*)l,
                                   16, 0, 0);
}

// ---------------- fp32 -> bf16 convert (vectorized) ----------------
__global__ __launch_bounds__(256) void cvt_f32_bf16(const float* __restrict__ in,
                                                    bf16* __restrict__ out, int n4) {
  int i = blockIdx.x * 256 + threadIdx.x;
  if (i < n4) {
    float4 v = *((const float4*)in + i);
    bf16x4 o;
    o[0] = (bf16)v.x; o[1] = (bf16)v.y; o[2] = (bf16)v.z; o[3] = (bf16)v.w;
    *((bf16x4*)out + i) = o;
  }
}

// ---------------- RoPE cos/sin table: [8192][32] ----------------
__global__ __launch_bounds__(256) void rope_table_k(float* __restrict__ cosT,
                                                    float* __restrict__ sinT) {
  int idx = blockIdx.x * 256 + threadIdx.x;   // 8192*32 = 262144
  int t = idx >> 5, j = idx & 31;
  float inv = exp2f(-(float)j * (13.287712379549449f / 32.0f));
  float fr = (float)t * inv;
  cosT[idx] = cosf(fr);
  sinT[idx] = sinf(fr);
}

// ---------------- bf16 GEMM, C[m,n] = sum_k A[m,k]*B[n,k] (B^T form) ----------------
// m97 structure + XCD-aware block swizzle. ROPE: fused rotary epilogue on cols < 2560.
template <int BSEL, int OUTF32, int ROPE>
__global__ __launch_bounds__(256) void gemm_bt(const bf16* __restrict__ A,
                                               const bf16* __restrict__ B0,
                                               const bf16* __restrict__ B1,
                                               const bf16* __restrict__ B2,
                                               void* __restrict__ Cout,
                                               const float* __restrict__ cosT,
                                               const float* __restrict__ sinT,
                                               int N, int K) {
  __shared__ bf16 As[128 * 32];
  __shared__ bf16 Bs[128 * 32];
  const int tid = threadIdx.x;
  const int lane = tid & 63, wave = tid >> 6;

  // XCD swizzle (bijective: grid count % 8 == 0 for all our launches)
  const int nx = gridDim.x;
  int lin = blockIdx.x + nx * blockIdx.y;
  const int cpx = (nx * gridDim.y) >> 3;
  lin = (lin & 7) * cpx + (lin >> 3);
  const int m0 = (lin % nx) * 128, n0 = (lin / nx) * 128;

  const int wr = (wave >> 1) * 64, wc = (wave & 1) * 64;

  f32x4 acc[4][4] = {};

  const int srow = tid >> 2;           // 0..63
  const int scol = (tid & 3) * 8;      // 0,8,16,24

  auto brow_ptr = [&](int n) -> const bf16* {
    if (BSEL) {
      if (n < 2048) return B0 + (size_t)n * K;
      if (n < 2560) return B1 + (size_t)(n - 2048) * K;
      return B2 + (size_t)(n - 2560) * K;
    }
    return B0 + (size_t)n * K;
  };

  const bf16* arow0 = A + (size_t)(m0 + srow) * K + scol;
  const bf16* arow1 = A + (size_t)(m0 + 64 + srow) * K + scol;
  const bf16* brow0 = brow_ptr(n0 + srow) + scol;
  const bf16* brow1 = brow_ptr(n0 + 64 + srow) + scol;
  bf16* ldsA = As + wave * 512;   // HW adds lane*16B
  bf16* ldsB = Bs + wave * 512;

  const int fr = lane & 15, fk = (lane >> 4) * 8;

  for (int k0 = 0; k0 < K; k0 += 32) {
    gload16(arow0 + k0, ldsA);
    gload16(arow1 + k0, ldsA + 2048);
    gload16(brow0 + k0, ldsB);
    gload16(brow1 + k0, ldsB + 2048);
    __syncthreads();

    bf16x8 af[4], bfr[4];
#pragma unroll
    for (int m = 0; m < 4; ++m)
      af[m] = *(const bf16x8*)(As + (wr + m * 16 + fr) * 32 + fk);
#pragma unroll
    for (int n = 0; n < 4; ++n)
      bfr[n] = *(const bf16x8*)(Bs + (wc + n * 16 + fr) * 32 + fk);
#pragma unroll
    for (int m = 0; m < 4; ++m)
#pragma unroll
      for (int n = 0; n < 4; ++n)
        acc[m][n] = mfma16(af[m], bfr[n], acc[m][n]);
    __syncthreads();
  }

  const int fc = lane & 15, fr4 = (lane >> 4) * 4;
  if (ROPE && (n0 + wc) < 2560) {
    // rotary epilogue: this 64-col window is one head; pair (j, j+32) = (acc n, n+2)
#pragma unroll
    for (int m = 0; m < 4; ++m)
#pragma unroll
      for (int i = 0; i < 4; ++i) {
        size_t row = (size_t)(m0 + wr + m * 16 + fr4 + i);
        bf16* base = (bf16*)Cout + row * (size_t)N + n0 + wc;
#pragma unroll
        for (int n = 0; n < 2; ++n) {
          int j = n * 16 + fc;                 // 0..31
          float c = cosT[row * 32 + j], sn = sinT[row * 32 + j];
          float x1 = acc[m][n][i], x2 = acc[m][n + 2][i];
          base[j]      = (bf16)(x1 * c - x2 * sn);
          base[j + 32] = (bf16)(x2 * c + x1 * sn);
        }
      }
  } else {
#pragma unroll
    for (int m = 0; m < 4; ++m)
#pragma unroll
      for (int i = 0; i < 4; ++i) {
        size_t row = (size_t)(m0 + wr + m * 16 + fr4 + i);
#pragma unroll
        for (int n = 0; n < 4; ++n) {
          int col = n0 + wc + n * 16 + fc;
          if (OUTF32)
            ((float*)Cout)[row * (size_t)N + col] = acc[m][n][i];
          else
            ((bf16*)Cout)[row * (size_t)N + col] = (bf16)acc[m][n][i];
        }
      }
  }
}

// ---------------- block-sparse attention, GQA-grouped, pipelined ----------------
// grid (128 qblocks, 8 kv heads), 1024 threads = 16 waves.
// wave w: head = kv*4 + (w>>2), q-rows [(w&3)*16, +16).
// Swapped QK^T: mfma(K, Q) -> lane holds 16 scores for ONE q-row (lane&15);
// softmax reduce = in-register tree + 2 shuffles.
// Ks single-buffer (gload_lds, XOR slot swizzle on global source);
// Vt double-buffer (packed-u32 transpose writes), V globals issued early (T14).
__global__ __launch_bounds__(1024) void attn_sparse(const bf16* __restrict__ qkv,
                                                    bf16* __restrict__ attn) {
  const int iblk = blockIdx.x;
  const int kv = blockIdx.y;
  const int tid = threadIdx.x, lane = tid & 63, wid = tid >> 6;
  const int hloc = wid >> 2;
  const int h = kv * 4 + hloc;
  const int rg = wid & 3;

  __shared__ bf16 Ks[64 * 64];        // [row r][slot s]: LDS[r][s] = K[r][s ^ (r&7)]
  __shared__ bf16 Vt[2][64 * 72];     // transposed: Vt[d][key], stride 72
  __shared__ bf16 Ps[16 * 16 * 68];   // per-wave 16 rows, stride 68

  const int qcol = h * 64, kcol = 2048 + kv * 64, vcol = 2560 + kv * 64;
  const size_t trow0 = (size_t)iblk * 64;
  const int fr = lane & 15, g4 = lane >> 4, fk = g4 * 8, fr4 = g4 * 4;

  // Q fragments in registers (B-operand of swapped QK^T)
  const bf16* qrow = qkv + (trow0 + rg * 16 + fr) * 3072 + qcol;
  bf16x8 bq0 = *(const bf16x8*)(qrow + fk);
  bf16x8 bq1 = *(const bf16x8*)(qrow + 32 + fk);

  float mrun = -INFINITY, lrun = 0.f;   // for this lane's q-row rg*16+fr
  f32x4 acc[4] = {};

  // staging roles
  const int kr = tid >> 3, ks = tid & 7;                  // tid<512: K row/slot
  const int vu = tid & 511, vp = vu & 31, vd0 = (vu >> 5) * 4;  // tid>=512: V
  const bool isK = (tid < 512);

  const int nsel = (iblk < 8) ? (iblk + 1) : 9;
  auto jof = [&](int js) { return (iblk < 8) ? js : ((js == 0) ? 0 : iblk - 8 + js); };

  // prologue: stage K(0), V(0)
  {
    const size_t krow = (size_t)jof(0) * 64;
    if (isK) {
      const bf16* src = qkv + (krow + kr) * 3072 + kcol + ((ks ^ (kr & 7)) * 8);
      gload16(src, Ks + (tid >> 6) * 512);
    } else {
      const bf16* v0p = qkv + (krow + 2 * vp) * 3072 + vcol + vd0;
      uint64_t a = *(const uint64_t*)v0p;
      uint64_t b = *(const uint64_t*)(v0p + 3072);
#pragma unroll
      for (int e = 0; e < 4; ++e) {
        uint32_t w = (uint32_t)((a >> (16 * e)) & 0xFFFF) |
                     ((uint32_t)((b >> (16 * e)) & 0xFFFF) << 16);
        *(uint32_t*)(&Vt[0][0] + (vd0 + e) * 72 + 2 * vp) = w;
      }
    }
  }
  __syncthreads();

  for (int js = 0; js < nsel; ++js) {
    const int cur = js & 1;
    const int jblk = jof(js);
    const bool pre = (js + 1 < nsel);

    // issue V(j+1) global loads early — latency hides under QK^T
    uint64_t va = 0, vb2 = 0;
    if (pre && !isK) {
      const bf16* v0p = qkv + ((size_t)jof(js + 1) * 64 + 2 * vp) * 3072 + vcol + vd0;
      va = *(const uint64_t*)v0p;
      vb2 = *(const uint64_t*)(v0p + 3072);
    }

    // S^T = K Q^T  (swapped: lane -> 16 scores of q-row fr)
    f32x4 s[4];
#pragma unroll
    for (int n = 0; n < 4; ++n) {
      const char* krowp = (const char*)Ks + (n * 16 + fr) * 128;
      bf16x8 kb0 = *(const bf16x8*)(krowp + ((g4 ^ (fr & 7)) << 4));
      bf16x8 kb1 = *(const bf16x8*)(krowp + (((4 + g4) ^ (fr & 7)) << 4));
      f32x4 z = {};
      z = mfma16(kb0, bq0, z);
      s[n] = mfma16(kb1, bq1, z);
    }

    __syncthreads();   // all waves done reading Ks -> safe to restage
    if (pre && isK) {
      const bf16* src = qkv + ((size_t)jof(js + 1) * 64 + kr) * 3072 + kcol +
                        ((ks ^ (kr & 7)) * 8);
      gload16(src, Ks + (tid >> 6) * 512);   // flies during softmax+PV
    }

    // scale + causal mask (diag block only)
    const bool diag = (jblk == iblk);
    const int qr = rg * 16 + fr;
#pragma unroll
    for (int n = 0; n < 4; ++n)
#pragma unroll
      for (int i = 0; i < 4; ++i) {
        float sv = s[n][i] * ATT_SCALE;
        if (diag && (n * 16 + fr4 + i) > qr) sv = NEG_BIG;
        s[n][i] = sv;
      }

    // softmax: in-register tree + 2 shuffles (lane owns q-row fr)
    float t0 = fmaxf(fmaxf(s[0][0], s[0][1]), fmaxf(s[0][2], s[0][3]));
    float t1 = fmaxf(fmaxf(s[1][0], s[1][1]), fmaxf(s[1][2], s[1][3]));
    float t2 = fmaxf(fmaxf(s[2][0], s[2][1]), fmaxf(s[2][2], s[2][3]));
    float t3 = fmaxf(fmaxf(s[3][0], s[3][1]), fmaxf(s[3][2], s[3][3]));
    float mx = fmaxf(fmaxf(t0, t1), fmaxf(t2, t3));
    mx = fmaxf(mx, __shfl_xor(mx, 16, 64));
    mx = fmaxf(mx, __shfl_xor(mx, 32, 64));
    float mnew = fmaxf(mrun, mx);
    float corr = __expf(mrun - mnew);
    mrun = mnew;
    float ps = 0.f;
#pragma unroll
    for (int n = 0; n < 4; ++n) {
      float p0 = __expf(s[n][0] - mnew), p1 = __expf(s[n][1] - mnew);
      float p2 = __expf(s[n][2] - mnew), p3 = __expf(s[n][3] - mnew);
      s[n][0] = p0; s[n][1] = p1; s[n][2] = p2; s[n][3] = p3;
      ps += (p0 + p1) + (p2 + p3);
    }
    ps += __shfl_xor(ps, 16, 64);
    ps += __shfl_xor(ps, 32, 64);
    lrun = lrun * corr + ps;

    // broadcast corr to this lane's acc rows (q = fr4+i)
    float cq[4];
#pragma unroll
    for (int i = 0; i < 4; ++i) cq[i] = __shfl(corr, fr4 + i, 64);
#pragma unroll
    for (int n = 0; n < 4; ++n)
#pragma unroll
      for (int i = 0; i < 4; ++i) acc[n][i] *= cq[i];

    // P -> LDS: lane writes its q-row fr, 4 consecutive k per n-block (b64 packs)
    bf16* pbase = Ps + wid * (16 * 68);
#pragma unroll
    for (int n = 0; n < 4; ++n) {
      bf16x4 pk;
#pragma unroll
      for (int i = 0; i < 4; ++i) pk[i] = (bf16)s[n][i];
      *(bf16x4*)(pbase + fr * 68 + n * 16 + fr4) = pk;
    }
    // A-frag read-back (same-wave LDS, in-order)
    bf16x8 pa0 = *(const bf16x8*)(pbase + fr * 68 + fk);
    bf16x8 pa1 = *(const bf16x8*)(pbase + fr * 68 + 32 + fk);

    // write V(j+1) regs -> Vt[cur^1] (late write, T14)
    if (pre && !isK) {
#pragma unroll
      for (int e = 0; e < 4; ++e) {
        uint32_t w = (uint32_t)((va >> (16 * e)) & 0xFFFF) |
                     ((uint32_t)((vb2 >> (16 * e)) & 0xFFFF) << 16);
        *(uint32_t*)(&Vt[cur ^ 1][0] + (vd0 + e) * 72 + 2 * vp) = w;
      }
    }

    // PV: O += P @ V
#pragma unroll
    for (int n = 0; n < 4; ++n) {
      bf16x8 vb0 = *(const bf16x8*)(&Vt[cur][0] + (n * 16 + fr) * 72 + fk);
      bf16x8 vb1 = *(const bf16x8*)(&Vt[cur][0] + (n * 16 + fr) * 72 + 32 + fk);
      acc[n] = mfma16(pa0, vb0, acc[n]);
      acc[n] = mfma16(pa1, vb1, acc[n]);
    }
    __syncthreads();   // K(j+1) drained (vmcnt), Vt[cur^1] written, Vt[cur] free
  }

  // epilogue: normalize and store bf16
  float lq[4];
#pragma unroll
  for (int i = 0; i < 4; ++i) lq[i] = __shfl(lrun, fr4 + i, 64);
#pragma unroll
  for (int i = 0; i < 4; ++i) {
    float rl = 1.0f / lq[i];
    size_t t = trow0 + rg * 16 + fr4 + i;
#pragma unroll
    for (int n = 0; n < 4; ++n)
      attn[t * 2048 + h * 64 + n * 16 + fr] = (bf16)(acc[n][i] * rl);
  }
}

// ---------------- launch ----------------
extern "C" void kernel_launch(void* const* d_in, const int* in_sizes, int n_in,
                              void* d_out, int out_size, void* d_ws, size_t ws_size,
                              hipStream_t stream) {
  (void)in_sizes; (void)n_in; (void)out_size; (void)ws_size;
  const float* hs = (const float*)d_in[0];
  const float* Wq = (const float*)d_in[1];
  const float* Wk = (const float*)d_in[2];
  const float* Wv = (const float*)d_in[3];
  const float* Wo = (const float*)d_in[4];
  float* out = (float*)d_out;

  char* ws = (char*)d_ws;
  bf16* hs16 = (bf16*)(ws + 0);              // 8192*2048*2  = 33554432
  bf16* qkv  = (bf16*)(ws + 33554432);       // 8192*3072*2  = 50331648
  bf16* attn = (bf16*)(ws + 83886080);       // 8192*2048*2  = 33554432
  bf16* wq16 = (bf16*)(ws + 117440512);      // 2048*2048*2  = 8388608
  bf16* wk16 = (bf16*)(ws + 125829120);      // 512*2048*2   = 2097152
  bf16* wv16 = (bf16*)(ws + 127926272);      // 512*2048*2   = 2097152
  bf16* wo16 = (bf16*)(ws + 130023424);      // 2048*2048*2  = 8388608
  float* cosT = (float*)(ws + 138412032);    // 8192*32*4    = 1048576
  float* sinT = (float*)(ws + 139460608);    // 8192*32*4    = 1048576

  cvt_f32_bf16<<<16384, 256, 0, stream>>>(hs, hs16, 4194304);
  cvt_f32_bf16<<<4096, 256, 0, stream>>>(Wq, wq16, 1048576);
  cvt_f32_bf16<<<1024, 256, 0, stream>>>(Wk, wk16, 262144);
  cvt_f32_bf16<<<1024, 256, 0, stream>>>(Wv, wv16, 262144);
  cvt_f32_bf16<<<4096, 256, 0, stream>>>(Wo, wo16, 1048576);
  rope_table_k<<<1024, 256, 0, stream>>>(cosT, sinT);

  // QKV projection: M=8192, N=3072, K=2048, RoPE fused into epilogue
  gemm_bt<1, 0, 1><<<dim3(64, 24), 256, 0, stream>>>(hs16, wq16, wk16, wv16, qkv,
                                                     cosT, sinT, 3072, 2048);
  attn_sparse<<<dim3(128, 8), 1024, 0, stream>>>(qkv, attn);
  // O projection: M=8192, N=2048, K=2048, fp32 out
  gemm_bt<0, 1, 0><<<dim3(64, 16), 256, 0, stream>>>(attn, wo16, wo16, wo16, out,
                                                     nullptr, nullptr, 2048, 2048);
}

// Round 4
// 319.393 us; speedup vs baseline: 1.4953x; 1.3913x over previous
//
#include <hip/hip_runtime.h>
#include <cstdint>
#include <cstddef>

typedef __bf16 bf16;
typedef __attribute__((ext_vector_type(8))) __bf16 bf16x8;
typedef __attribute__((ext_vector_type(4))) __bf16 bf16x4;
typedef __attribute__((ext_vector_type(4))) float f32x4;

#define ATT_SCALE 0.125f   // 1/sqrt(64)
#define NEG_BIG  -1000000000.0f

__device__ __forceinline__ f32x4 mfma16(bf16x8 a, bf16x8 b, f32x4 c) {
  return __builtin_amdgcn_mfma_f32_16x16x32_bf16(a, b, c, 0, 0, 0);
}

__device__ __forceinline__ void gload16(const bf16* g, bf16* l) {
  __builtin_amdgcn_global_load_lds((__attribute__((address_space(1))) void*)g,
                                   (__attribute__((address_space(3))) void*)l,
                                   16, 0, 0);
}

// ---------------- fused prep: all fp32->bf16 converts + RoPE table ----------------
__global__ __launch_bounds__(256) void prep_all(const float* __restrict__ hs,
                                                const float* __restrict__ Wq,
                                                const float* __restrict__ Wk,
                                                const float* __restrict__ Wv,
                                                const float* __restrict__ Wo,
                                                bf16* __restrict__ hs16, bf16* __restrict__ wq16,
                                                bf16* __restrict__ wk16, bf16* __restrict__ wv16,
                                                bf16* __restrict__ wo16,
                                                float* __restrict__ cosT, float* __restrict__ sinT) {
  int b = blockIdx.x, t = threadIdx.x;
  const float* src; bf16* dst; int i;
  if (b < 16384)      { src = hs; dst = hs16; i = b * 256 + t; }
  else if (b < 20480) { src = Wq; dst = wq16; i = (b - 16384) * 256 + t; }
  else if (b < 21504) { src = Wk; dst = wk16; i = (b - 20480) * 256 + t; }
  else if (b < 22528) { src = Wv; dst = wv16; i = (b - 21504) * 256 + t; }
  else if (b < 26624) { src = Wo; dst = wo16; i = (b - 22528) * 256 + t; }
  else {
    int idx = (b - 26624) * 256 + t;   // 8192*32
    int tt = idx >> 5, j = idx & 31;
    float inv = exp2f(-(float)j * (13.287712379549449f / 32.0f));
    float fr = (float)tt * inv;
    cosT[idx] = cosf(fr); sinT[idx] = sinf(fr);
    return;
  }
  float4 v = *((const float4*)src + i);
  bf16x4 o;
  o[0] = (bf16)v.x; o[1] = (bf16)v.y; o[2] = (bf16)v.z; o[3] = (bf16)v.w;
  *((bf16x4*)dst + i) = o;
}

// ---------------- 256x256 bf16 GEMM, counted-vmcnt pipeline ----------------
// C[m,n] = sum_k A[m,k]*B[n,k]. BK=32, 512 threads = 8 waves (2M x 4N),
// per-wave output 128x64 (acc[8][4] f32x4). LDS: 4-buffer rotation, 4x(A 16KB + B 16KB)
// = 128 KB. Per K-tile: one s_waitcnt vmcnt(8) + one s_barrier; stage kt+3 during kt.
// LDS chunk swizzle: storage chunk p of row r holds logical col-chunk p^((r>>1)&3)
// (applied on GLOBAL source; LDS dest linear for global_load_lds; reads apply same XOR).
template <int BSEL, int OUTF32, int ROPE>
__global__ __launch_bounds__(512, 2) void gemm256(const bf16* __restrict__ A,
                                                  const bf16* __restrict__ B0,
                                                  const bf16* __restrict__ B1,
                                                  const bf16* __restrict__ B2,
                                                  void* __restrict__ Cout,
                                                  const float* __restrict__ cosT,
                                                  const float* __restrict__ sinT,
                                                  int N, int K) {
  __shared__ bf16 Asm[4][8192];   // [buf][256 rows x 32 k]
  __shared__ bf16 Bsm[4][8192];
  const int tid = threadIdx.x, lane = tid & 63, wid = tid >> 6;
  const int m0 = blockIdx.x * 256, n0 = blockIdx.y * 256;
  const int wr = wid >> 2, wc = wid & 3;      // wave row (0..1), col (0..3)
  const int fr = lane & 15, g4 = lane >> 4;
  const int sw8 = (g4 ^ ((fr >> 1) & 3)) * 8; // per-lane swizzled k-chunk offset (elems)

  f32x4 acc[8][4] = {};

  auto brow = [&](int n) -> const bf16* {
    if (BSEL) {
      if (n < 2048) return B0 + (size_t)n * K;
      if (n < 2560) return B1 + (size_t)(n - 2048) * K;
      return B2 + (size_t)(n - 2560) * K;
    }
    return B0 + (size_t)n * K;
  };

  // staging: per thread 2 chunks of A + 2 of B per K-tile. chunk c -> row c>>2,
  // logical col-chunk (c&3)^((r>>1)&3); LDS dest = c*16 bytes (linear).
  const bf16* aS0; const bf16* aS1; const bf16* bS0; const bf16* bS1;
  {
    int c0 = tid, r0 = c0 >> 2, l0 = (c0 & 3) ^ ((r0 >> 1) & 3);
    int c1 = 512 + tid, r1 = c1 >> 2, l1 = (c1 & 3) ^ ((r1 >> 1) & 3);
    aS0 = A + (size_t)(m0 + r0) * K + l0 * 8;
    aS1 = A + (size_t)(m0 + r1) * K + l1 * 8;
    bS0 = brow(n0 + r0) + l0 * 8;
    bS1 = brow(n0 + r1) + l1 * 8;
  }
  const int dst0 = (wid * 64) * 8;          // + HW lane*16B
  const int dst1 = (512 + wid * 64) * 8;

#define STAGE_A(kt) { bf16* d = &Asm[(kt) & 3][0]; \
    gload16(aS0 + (kt) * 32, d + dst0); gload16(aS1 + (kt) * 32, d + dst1); }
#define STAGE_B(kt) { bf16* d = &Bsm[(kt) & 3][0]; \
    gload16(bS0 + (kt) * 32, d + dst0); gload16(bS1 + (kt) * 32, d + dst1); }

#define KTILE(kt, VM, STG) { \
    asm volatile("s_waitcnt vmcnt(" VM ")" ::: "memory"); \
    __builtin_amdgcn_s_barrier(); \
    __builtin_amdgcn_sched_barrier(0); \
    const bf16* Ab = &Asm[(kt) & 3][0]; \
    const bf16* Bb = &Bsm[(kt) & 3][0]; \
    bf16x8 bfr[4], af[4]; \
    _Pragma("unroll") for (int nf = 0; nf < 4; ++nf) \
      bfr[nf] = *(const bf16x8*)(Bb + (wc * 64 + nf * 16 + fr) * 32 + sw8); \
    _Pragma("unroll") for (int mf = 0; mf < 4; ++mf) \
      af[mf] = *(const bf16x8*)(Ab + (wr * 128 + mf * 16 + fr) * 32 + sw8); \
    if (STG) STAGE_A((kt) + 3); \
    __builtin_amdgcn_s_setprio(1); \
    _Pragma("unroll") for (int mf = 0; mf < 4; ++mf) \
      _Pragma("unroll") for (int nf = 0; nf < 4; ++nf) \
        acc[mf][nf] = mfma16(af[mf], bfr[nf], acc[mf][nf]); \
    __builtin_amdgcn_s_setprio(0); \
    _Pragma("unroll") for (int mf = 0; mf < 4; ++mf) \
      af[mf] = *(const bf16x8*)(Ab + (wr * 128 + 64 + mf * 16 + fr) * 32 + sw8); \
    if (STG) STAGE_B((kt) + 3); \
    __builtin_amdgcn_s_setprio(1); \
    _Pragma("unroll") for (int mf = 0; mf < 4; ++mf) \
      _Pragma("unroll") for (int nf = 0; nf < 4; ++nf) \
        acc[4 + mf][nf] = mfma16(af[mf], bfr[nf], acc[4 + mf][nf]); \
    __builtin_amdgcn_s_setprio(0); \
  }

  // prologue: 3 K-tiles in flight
  STAGE_A(0); STAGE_B(0);
  STAGE_A(1); STAGE_B(1);
  STAGE_A(2); STAGE_B(2);

  const int NT = K >> 5;   // 64
  for (int kt = 0; kt < NT - 3; ++kt) KTILE(kt, "8", 1);
  KTILE(NT - 3, "8", 0);
  KTILE(NT - 2, "4", 0);
  KTILE(NT - 1, "0", 0);
#undef KTILE
#undef STAGE_A
#undef STAGE_B

  // epilogue
  const int fc = lane & 15, fr4 = (lane >> 4) * 4;
  if (ROPE && (n0 + wc * 64) < 2560) {
#pragma unroll
    for (int am = 0; am < 8; ++am)
#pragma unroll
      for (int i = 0; i < 4; ++i) {
        size_t row = (size_t)(m0 + wr * 128 + am * 16 + fr4 + i);
        bf16* base = (bf16*)Cout + row * (size_t)N + n0 + wc * 64;
#pragma unroll
        for (int nf = 0; nf < 2; ++nf) {
          int j = nf * 16 + fc;
          float c = cosT[row * 32 + j], sn = sinT[row * 32 + j];
          float x1 = acc[am][nf][i], x2 = acc[am][nf + 2][i];
          base[j]      = (bf16)(x1 * c - x2 * sn);
          base[j + 32] = (bf16)(x2 * c + x1 * sn);
        }
      }
  } else {
#pragma unroll
    for (int am = 0; am < 8; ++am)
#pragma unroll
      for (int i = 0; i < 4; ++i) {
        size_t row = (size_t)(m0 + wr * 128 + am * 16 + fr4 + i);
#pragma unroll
        for (int nf = 0; nf < 4; ++nf) {
          int col = n0 + wc * 64 + nf * 16 + fc;
          if (OUTF32)
            ((float*)Cout)[row * (size_t)N + col] = acc[am][nf][i];
          else
            ((bf16*)Cout)[row * (size_t)N + col] = (bf16)acc[am][nf][i];
        }
      }
  }
}

// ---------------- block-sparse attention, GQA-grouped, pipelined ----------------
// (unchanged from round 3 — validated)
__global__ __launch_bounds__(1024) void attn_sparse(const bf16* __restrict__ qkv,
                                                    bf16* __restrict__ attn) {
  const int iblk = blockIdx.x;
  const int kv = blockIdx.y;
  const int tid = threadIdx.x, lane = tid & 63, wid = tid >> 6;
  const int hloc = wid >> 2;
  const int h = kv * 4 + hloc;
  const int rg = wid & 3;

  __shared__ bf16 Ks[64 * 64];
  __shared__ bf16 Vt[2][64 * 72];
  __shared__ bf16 Ps[16 * 16 * 68];

  const int qcol = h * 64, kcol = 2048 + kv * 64, vcol = 2560 + kv * 64;
  const size_t trow0 = (size_t)iblk * 64;
  const int fr = lane & 15, g4 = lane >> 4, fk = g4 * 8, fr4 = g4 * 4;

  const bf16* qrow = qkv + (trow0 + rg * 16 + fr) * 3072 + qcol;
  bf16x8 bq0 = *(const bf16x8*)(qrow + fk);
  bf16x8 bq1 = *(const bf16x8*)(qrow + 32 + fk);

  float mrun = -INFINITY, lrun = 0.f;
  f32x4 acc[4] = {};

  const int kr = tid >> 3, ks = tid & 7;
  const int vu = tid & 511, vp = vu & 31, vd0 = (vu >> 5) * 4;
  const bool isK = (tid < 512);

  const int nsel = (iblk < 8) ? (iblk + 1) : 9;
  auto jof = [&](int js) { return (iblk < 8) ? js : ((js == 0) ? 0 : iblk - 8 + js); };

  {
    const size_t krow = (size_t)jof(0) * 64;
    if (isK) {
      const bf16* src = qkv + (krow + kr) * 3072 + kcol + ((ks ^ (kr & 7)) * 8);
      gload16(src, Ks + (tid >> 6) * 512);
    } else {
      const bf16* v0p = qkv + (krow + 2 * vp) * 3072 + vcol + vd0;
      uint64_t a = *(const uint64_t*)v0p;
      uint64_t b = *(const uint64_t*)(v0p + 3072);
#pragma unroll
      for (int e = 0; e < 4; ++e) {
        uint32_t w = (uint32_t)((a >> (16 * e)) & 0xFFFF) |
                     ((uint32_t)((b >> (16 * e)) & 0xFFFF) << 16);
        *(uint32_t*)(&Vt[0][0] + (vd0 + e) * 72 + 2 * vp) = w;
      }
    }
  }
  __syncthreads();

  for (int js = 0; js < nsel; ++js) {
    const int cur = js & 1;
    const int jblk = jof(js);
    const bool pre = (js + 1 < nsel);

    uint64_t va = 0, vb2 = 0;
    if (pre && !isK) {
      const bf16* v0p = qkv + ((size_t)jof(js + 1) * 64 + 2 * vp) * 3072 + vcol + vd0;
      va = *(const uint64_t*)v0p;
      vb2 = *(const uint64_t*)(v0p + 3072);
    }

    f32x4 s[4];
#pragma unroll
    for (int n = 0; n < 4; ++n) {
      const char* krowp = (const char*)Ks + (n * 16 + fr) * 128;
      bf16x8 kb0 = *(const bf16x8*)(krowp + ((g4 ^ (fr & 7)) << 4));
      bf16x8 kb1 = *(const bf16x8*)(krowp + (((4 + g4) ^ (fr & 7)) << 4));
      f32x4 z = {};
      z = mfma16(kb0, bq0, z);
      s[n] = mfma16(kb1, bq1, z);
    }

    __syncthreads();
    if (pre && isK) {
      const bf16* src = qkv + ((size_t)jof(js + 1) * 64 + kr) * 3072 + kcol +
                        ((ks ^ (kr & 7)) * 8);
      gload16(src, Ks + (tid >> 6) * 512);
    }

    const bool diag = (jblk == iblk);
    const int qr = rg * 16 + fr;
#pragma unroll
    for (int n = 0; n < 4; ++n)
#pragma unroll
      for (int i = 0; i < 4; ++i) {
        float sv = s[n][i] * ATT_SCALE;
        if (diag && (n * 16 + fr4 + i) > qr) sv = NEG_BIG;
        s[n][i] = sv;
      }

    float t0 = fmaxf(fmaxf(s[0][0], s[0][1]), fmaxf(s[0][2], s[0][3]));
    float t1 = fmaxf(fmaxf(s[1][0], s[1][1]), fmaxf(s[1][2], s[1][3]));
    float t2 = fmaxf(fmaxf(s[2][0], s[2][1]), fmaxf(s[2][2], s[2][3]));
    float t3 = fmaxf(fmaxf(s[3][0], s[3][1]), fmaxf(s[3][2], s[3][3]));
    float mx = fmaxf(fmaxf(t0, t1), fmaxf(t2, t3));
    mx = fmaxf(mx, __shfl_xor(mx, 16, 64));
    mx = fmaxf(mx, __shfl_xor(mx, 32, 64));
    float mnew = fmaxf(mrun, mx);
    float corr = __expf(mrun - mnew);
    mrun = mnew;
    float ps = 0.f;
#pragma unroll
    for (int n = 0; n < 4; ++n) {
      float p0 = __expf(s[n][0] - mnew), p1 = __expf(s[n][1] - mnew);
      float p2 = __expf(s[n][2] - mnew), p3 = __expf(s[n][3] - mnew);
      s[n][0] = p0; s[n][1] = p1; s[n][2] = p2; s[n][3] = p3;
      ps += (p0 + p1) + (p2 + p3);
    }
    ps += __shfl_xor(ps, 16, 64);
    ps += __shfl_xor(ps, 32, 64);
    lrun = lrun * corr + ps;

    float cq[4];
#pragma unroll
    for (int i = 0; i < 4; ++i) cq[i] = __shfl(corr, fr4 + i, 64);
#pragma unroll
    for (int n = 0; n < 4; ++n)
#pragma unroll
      for (int i = 0; i < 4; ++i) acc[n][i] *= cq[i];

    bf16* pbase = Ps + wid * (16 * 68);
#pragma unroll
    for (int n = 0; n < 4; ++n) {
      bf16x4 pk;
#pragma unroll
      for (int i = 0; i < 4; ++i) pk[i] = (bf16)s[n][i];
      *(bf16x4*)(pbase + fr * 68 + n * 16 + fr4) = pk;
    }
    bf16x8 pa0 = *(const bf16x8*)(pbase + fr * 68 + fk);
    bf16x8 pa1 = *(const bf16x8*)(pbase + fr * 68 + 32 + fk);

    if (pre && !isK) {
#pragma unroll
      for (int e = 0; e < 4; ++e) {
        uint32_t w = (uint32_t)((va >> (16 * e)) & 0xFFFF) |
                     ((uint32_t)((vb2 >> (16 * e)) & 0xFFFF) << 16);
        *(uint32_t*)(&Vt[cur ^ 1][0] + (vd0 + e) * 72 + 2 * vp) = w;
      }
    }

#pragma unroll
    for (int n = 0; n < 4; ++n) {
      bf16x8 vb0 = *(const bf16x8*)(&Vt[cur][0] + (n * 16 + fr) * 72 + fk);
      bf16x8 vb1 = *(const bf16x8*)(&Vt[cur][0] + (n * 16 + fr) * 72 + 32 + fk);
      acc[n] = mfma16(pa0, vb0, acc[n]);
      acc[n] = mfma16(pa1, vb1, acc[n]);
    }
    __syncthreads();
  }

  float lq[4];
#pragma unroll
  for (int i = 0; i < 4; ++i) lq[i] = __shfl(lrun, fr4 + i, 64);
#pragma unroll
  for (int i = 0; i < 4; ++i) {
    float rl = 1.0f / lq[i];
    size_t t = trow0 + rg * 16 + fr4 + i;
#pragma unroll
    for (int n = 0; n < 4; ++n)
      attn[t * 2048 + h * 64 + n * 16 + fr] = (bf16)(acc[n][i] * rl);
  }
}

// ---------------- launch ----------------
extern "C" void kernel_launch(void* const* d_in, const int* in_sizes, int n_in,
                              void* d_out, int out_size, void* d_ws, size_t ws_size,
                              hipStream_t stream) {
  (void)in_sizes; (void)n_in; (void)out_size; (void)ws_size;
  const float* hs = (const float*)d_in[0];
  const float* Wq = (const float*)d_in[1];
  const float* Wk = (const float*)d_in[2];
  const float* Wv = (const float*)d_in[3];
  const float* Wo = (const float*)d_in[4];
  float* out = (float*)d_out;

  char* ws = (char*)d_ws;
  bf16* hs16 = (bf16*)(ws + 0);              // 8192*2048*2  = 33554432
  bf16* qkv  = (bf16*)(ws + 33554432);       // 8192*3072*2  = 50331648
  bf16* attn = (bf16*)(ws + 83886080);       // 8192*2048*2  = 33554432
  bf16* wq16 = (bf16*)(ws + 117440512);      // 2048*2048*2  = 8388608
  bf16* wk16 = (bf16*)(ws + 125829120);      // 512*2048*2   = 2097152
  bf16* wv16 = (bf16*)(ws + 127926272);      // 512*2048*2   = 2097152
  bf16* wo16 = (bf16*)(ws + 130023424);      // 2048*2048*2  = 8388608
  float* cosT = (float*)(ws + 138412032);    // 8192*32*4    = 1048576
  float* sinT = (float*)(ws + 139460608);    // 8192*32*4    = 1048576

  prep_all<<<27648, 256, 0, stream>>>(hs, Wq, Wk, Wv, Wo,
                                      hs16, wq16, wk16, wv16, wo16, cosT, sinT);

  // QKV projection: M=8192, N=3072, K=2048, RoPE fused into epilogue
  gemm256<1, 0, 1><<<dim3(32, 12), 512, 0, stream>>>(hs16, wq16, wk16, wv16, qkv,
                                                     cosT, sinT, 3072, 2048);
  attn_sparse<<<dim3(128, 8), 1024, 0, stream>>>(qkv, attn);
  // O projection: M=8192, N=2048, K=2048, fp32 out
  gemm256<0, 1, 0><<<dim3(32, 8), 512, 0, stream>>>(attn, wo16, wo16, wo16, out,
                                                    nullptr, nullptr, 2048, 2048);
}